// Round 3
// baseline (979.828 us; speedup 1.0000x reference)
//
#include <hip/hip_runtime.h>
#include <hip/hip_bf16.h>
#include <math.h>

#define SEQ 2048
#define DIM 4096
#define NH 32
#define HD 128
#define NKV 8
#define NREP 4
#define BLOCK 64
#define NBLK 32
#define TOPK 8
#define KVDIM (NKV * HD)   // 1024
#define SCALE 0.08838834764831845f

// ---------------- bf16 helpers ----------------
__device__ inline unsigned short f2b(float f) {
    __hip_bfloat16 h = __float2bfloat16(f);
    return *reinterpret_cast<unsigned short*>(&h);
}
__device__ inline float bitsf(unsigned int u) {
    union { float f; unsigned int i; } x; x.i = u; return x.f;
}
__device__ inline float b2f(unsigned short us) { return bitsf(((unsigned int)us) << 16); }
__device__ inline void unpack2(unsigned int w0, float* o) {
    o[0] = bitsf(w0 << 16);
    o[1] = bitsf(w0 & 0xffff0000u);
}
__device__ inline void unpack4(uint2 w, float* o) { unpack2(w.x, o); unpack2(w.y, o + 2); }
__device__ inline void unpack8(uint4 w, float* o) {
    unpack2(w.x, o); unpack2(w.y, o + 2); unpack2(w.z, o + 4); unpack2(w.w, o + 6);
}
__device__ inline float dot4f(float4 a, float4 b) {
    return a.x * b.x + a.y * b.y + a.z * b.z + a.w * b.w;
}

// ---------------- MFMA GEMM: C(MxN) = A(MxK) @ Bt(NxK)^T, bf16 in / fp32 out -------
typedef __attribute__((ext_vector_type(8))) short bfrag;
typedef __attribute__((ext_vector_type(4))) float ffrag;

__device__ __forceinline__ void gl_lds16(const void* g, void* l) {
    __builtin_amdgcn_global_load_lds((const __attribute__((address_space(1))) void*)g,
                                     (__attribute__((address_space(3))) void*)l, 16, 0, 0);
}

template <bool SPLIT>
__global__ __launch_bounds__(256) void mfma_gemm(const unsigned short* __restrict__ Ah,
                                                 const unsigned short* __restrict__ Al,
                                                 const unsigned short* __restrict__ Bh,
                                                 const unsigned short* __restrict__ Bl,
                                                 float* __restrict__ C,
                                                 int M, int N, int K) {
    __shared__ short As[(SPLIT ? 2 : 1) * 4096];  // [hi(,lo)][128][32]
    __shared__ short Bs[(SPLIT ? 2 : 1) * 4096];

    const int tid = threadIdx.x;
    const int lane = tid & 63;
    const int w = tid >> 6;
    const int wm = (w >> 1) * 64;
    const int wn = (w & 1) * 64;
    const int m = lane & 15;
    const int quad = lane >> 4;

    // XCD-aware bijective swizzle (nwg % 8 == 0 for all grids used here)
    int bx = blockIdx.x, by = blockIdx.y;
    {
        const int nwg = gridDim.x * gridDim.y;
        if ((nwg & 7) == 0) {
            const int flat = by * gridDim.x + bx;
            const int nper = nwg >> 3;
            const int swz = (flat & 7) * nper + (flat >> 3);
            bx = swz % gridDim.x;
            by = swz / gridDim.x;
        }
    }
    const int bm = by * 128;
    const int bn = bx * 128;

    const int r0 = tid >> 2;
    const int c0 = (tid & 3) * 8;
    const size_t aoff0 = (size_t)(bm + r0) * K + c0;
    const size_t aoff1 = (size_t)(bm + r0 + 64) * K + c0;
    const size_t boff0 = (size_t)(bn + r0) * K + c0;
    const size_t boff1 = (size_t)(bn + r0 + 64) * K + c0;

    ffrag acc[4][4];
    const ffrag z = {0.f, 0.f, 0.f, 0.f};
#pragma unroll
    for (int i = 0; i < 4; ++i)
#pragma unroll
        for (int j = 0; j < 4; ++j) acc[i][j] = z;

    for (int kt = 0; kt < K; kt += 32) {
        __syncthreads();
        gl_lds16(Ah + aoff0 + kt, As + tid * 8);
        gl_lds16(Ah + aoff1 + kt, As + 2048 + tid * 8);
        gl_lds16(Bh + boff0 + kt, Bs + tid * 8);
        gl_lds16(Bh + boff1 + kt, Bs + 2048 + tid * 8);
        if constexpr (SPLIT) {
            gl_lds16(Al + aoff0 + kt, As + 4096 + tid * 8);
            gl_lds16(Al + aoff1 + kt, As + 6144 + tid * 8);
            gl_lds16(Bl + boff0 + kt, Bs + 4096 + tid * 8);
            gl_lds16(Bl + boff1 + kt, Bs + 6144 + tid * 8);
        }
        __syncthreads();

        bfrag ah[4], bh[4];
#pragma unroll
        for (int i = 0; i < 4; ++i)
            ah[i] = *(const bfrag*)(As + (wm + i * 16 + m) * 32 + quad * 8);
#pragma unroll
        for (int j = 0; j < 4; ++j)
            bh[j] = *(const bfrag*)(Bs + (wn + j * 16 + m) * 32 + quad * 8);
        if constexpr (SPLIT) {
            bfrag al[4], bl[4];
#pragma unroll
            for (int i = 0; i < 4; ++i)
                al[i] = *(const bfrag*)(As + 4096 + (wm + i * 16 + m) * 32 + quad * 8);
#pragma unroll
            for (int j = 0; j < 4; ++j)
                bl[j] = *(const bfrag*)(Bs + 4096 + (wn + j * 16 + m) * 32 + quad * 8);
#pragma unroll
            for (int i = 0; i < 4; ++i)
#pragma unroll
                for (int j = 0; j < 4; ++j) {
                    acc[i][j] = __builtin_amdgcn_mfma_f32_16x16x32_bf16(ah[i], bh[j], acc[i][j], 0, 0, 0);
                    acc[i][j] = __builtin_amdgcn_mfma_f32_16x16x32_bf16(ah[i], bl[j], acc[i][j], 0, 0, 0);
                    acc[i][j] = __builtin_amdgcn_mfma_f32_16x16x32_bf16(al[i], bh[j], acc[i][j], 0, 0, 0);
                }
        } else {
#pragma unroll
            for (int i = 0; i < 4; ++i)
#pragma unroll
                for (int j = 0; j < 4; ++j)
                    acc[i][j] = __builtin_amdgcn_mfma_f32_16x16x32_bf16(ah[i], bh[j], acc[i][j], 0, 0, 0);
        }
    }

#pragma unroll
    for (int i = 0; i < 4; ++i)
#pragma unroll
        for (int j = 0; j < 4; ++j)
#pragma unroll
            for (int r = 0; r < 4; ++r)
                C[(size_t)(bm + wm + i * 16 + quad * 4 + r) * N + bn + wn + j * 16 + m] =
                    acc[i][j][r];
}

// ---------------- transpose + bf16 split: W(KxN fp32) -> T(NxK bf16 hi[,lo]) --------
__global__ __launch_bounds__(256) void transpose_conv(const float* __restrict__ W,
                                                      unsigned short* __restrict__ Th,
                                                      unsigned short* __restrict__ Tl,
                                                      int K, int N, int rowoff) {
    __shared__ float tile[32][36];
    const int k0 = blockIdx.y * 32, n0 = blockIdx.x * 32;
    const int t = threadIdx.x;
    const int r = t >> 3, c4 = (t & 7) * 4;
    *(float4*)&tile[r][c4] = *(const float4*)(W + (size_t)(k0 + r) * N + n0 + c4);
    __syncthreads();
    float v0 = tile[c4 + 0][r], v1 = tile[c4 + 1][r], v2 = tile[c4 + 2][r], v3 = tile[c4 + 3][r];
    ushort4 h;
    h.x = f2b(v0); h.y = f2b(v1); h.z = f2b(v2); h.w = f2b(v3);
    const size_t ooff = (size_t)(rowoff + n0 + r) * K + k0 + c4;
    *(ushort4*)(Th + ooff) = h;
    if (Tl) {
        ushort4 l;
        l.x = f2b(v0 - b2f(h.x)); l.y = f2b(v1 - b2f(h.y));
        l.z = f2b(v2 - b2f(h.z)); l.w = f2b(v3 - b2f(h.w));
        *(ushort4*)(Tl + ooff) = l;
    }
}

// ---------------- elementwise fp32 -> bf16 hi (+lo) ----------------
__global__ void conv_hilo(const float* __restrict__ X, unsigned short* __restrict__ H,
                          unsigned short* __restrict__ L) {
    const int i = (blockIdx.x * blockDim.x + threadIdx.x) * 4;
    const float4 x = *(const float4*)(X + i);
    ushort4 h;
    h.x = f2b(x.x); h.y = f2b(x.y); h.z = f2b(x.z); h.w = f2b(x.w);
    *(ushort4*)(H + i) = h;
    if (L) {
        ushort4 l;
        l.x = f2b(x.x - b2f(h.x)); l.y = f2b(x.y - b2f(h.y));
        l.z = f2b(x.z - b2f(h.z)); l.w = f2b(x.w - b2f(h.w));
        *(ushort4*)(L + i) = l;
    }
}

// ---------------- K half of kvf -> bf16 row-major [SEQ][KVDIM] ----------------
__global__ void kconv_kernel(const float* __restrict__ kvf, unsigned short* __restrict__ kb) {
    const int i = (blockIdx.x * blockDim.x + threadIdx.x) * 4;
    const int s = i >> 10, c = i & 1023;
    const float4 x = *(const float4*)(kvf + (size_t)s * 2048 + c);
    ushort4 h;
    h.x = f2b(x.x); h.y = f2b(x.y); h.z = f2b(x.z); h.w = f2b(x.w);
    *(ushort4*)(kb + (size_t)s * 1024 + c) = h;
}

// ---------------- V half of kvf -> bf16 TRANSPOSED [KVDIM][SEQ] ----------------
__global__ __launch_bounds__(256) void vtrans_kernel(const float* __restrict__ kvf,
                                                     unsigned short* __restrict__ vt) {
    __shared__ unsigned short tile[64][72];
    const int s0 = blockIdx.x * 64;
    const int c0 = blockIdx.y * 64;
    const int t = threadIdx.x;
    const int r = t >> 4;            // 0..15
    const int c4 = (t & 15) * 4;     // 0..60
#pragma unroll
    for (int u = 0; u < 4; ++u) {
        const float4 x = *(const float4*)(kvf + (size_t)(s0 + u * 16 + r) * 2048 + 1024 + c0 + c4);
        ushort4 hh;
        hh.x = f2b(x.x); hh.y = f2b(x.y); hh.z = f2b(x.z); hh.w = f2b(x.w);
        *(ushort4*)(&tile[u * 16 + r][c4]) = hh;
    }
    __syncthreads();
    const int cc = t >> 2;           // 0..63
    const int sg = (t & 3) * 16;     // 0,16,32,48
    union { unsigned short s[16]; uint4 v[2]; } bb;
#pragma unroll
    for (int i = 0; i < 16; ++i) bb.s[i] = tile[sg + i][cc];
    unsigned short* op = vt + (size_t)(c0 + cc) * 2048 + s0 + sg;
    *(uint4*)op = bb.v[0];
    *(uint4*)(op + 8) = bb.v[1];
}

// ---------------- fallback fp32 GEMM (R2/R3 proven) ----------------
__global__ __launch_bounds__(256) void gemm_kernel(const float* __restrict__ A,
                                                   const float* __restrict__ B,
                                                   float* __restrict__ C,
                                                   int M, int N, int K) {
    __shared__ __align__(16) float As[16][68];
    __shared__ __align__(16) float Bs[16][68];

    const int tid = threadIdx.x;
    const int bm = blockIdx.y * 64;
    const int bn = blockIdx.x * 64;
    const int tm = (tid >> 4) * 4;
    const int tn = (tid & 15) * 4;

    float acc[4][4] = {};

    for (int k0 = 0; k0 < K; k0 += 16) {
        {
            const int mm = tid >> 2;
            const int kk = (tid & 3) * 4;
            const float* ap = A + (size_t)(bm + mm) * K + k0 + kk;
            const float4 a4 = *reinterpret_cast<const float4*>(ap);
            As[kk + 0][mm] = a4.x;
            As[kk + 1][mm] = a4.y;
            As[kk + 2][mm] = a4.z;
            As[kk + 3][mm] = a4.w;
        }
        {
            const int kk = tid >> 4;
            const int n = (tid & 15) * 4;
            const float* bp = B + (size_t)(k0 + kk) * N + bn + n;
            *reinterpret_cast<float4*>(&Bs[kk][n]) = *reinterpret_cast<const float4*>(bp);
        }
        __syncthreads();
#pragma unroll
        for (int kk = 0; kk < 16; ++kk) {
            const float4 a4 = *reinterpret_cast<const float4*>(&As[kk][tm]);
            const float4 b4 = *reinterpret_cast<const float4*>(&Bs[kk][tn]);
            const float av[4] = {a4.x, a4.y, a4.z, a4.w};
            const float bv[4] = {b4.x, b4.y, b4.z, b4.w};
#pragma unroll
            for (int i = 0; i < 4; ++i)
#pragma unroll
                for (int j = 0; j < 4; ++j) acc[i][j] += av[i] * bv[j];
        }
        __syncthreads();
    }
#pragma unroll
    for (int i = 0; i < 4; ++i)
#pragma unroll
        for (int j = 0; j < 4; ++j)
            C[(size_t)(bm + tm + i) * N + bn + tn + j] = acc[i][j];
}

// ---------------- RoPE (in place, fp32 buffer; row stride param) ----------------
__global__ void rope_kernel(float* __restrict__ x, const float* __restrict__ cosb,
                            const float* __restrict__ sinb, int nh, int stride) {
    const int idx = blockIdx.x * blockDim.x + threadIdx.x;
    const int i = idx & 63;
    const int h = (idx >> 6) % nh;
    const int pos = idx / (64 * nh);
    const float c = cosb[pos * 64 + i];
    const float s = sinb[pos * 64 + i];
    float* p = x + (size_t)pos * stride + h * HD + 2 * i;
    const float x0 = p[0], x1 = p[1];
    p[0] = x0 * c - x1 * s;
    p[1] = x0 * s + x1 * c;
}

// ---------------- Block means of K ----------------
__global__ void blkmean_kernel(const float* __restrict__ k, float* __restrict__ kblk,
                               int stride) {
    const int idx = blockIdx.x * blockDim.x + threadIdx.x;
    const int d = idx & 127;
    const int blk = (idx >> 7) & 31;
    const int kv = idx >> 12;
    float s = 0.f;
#pragma unroll 8
    for (int r = 0; r < BLOCK; ++r)
        s += k[(size_t)(blk * BLOCK + r) * stride + kv * HD + d];
    kblk[idx] = s * (1.f / 64.f);
}

// ---------------- MFMA flash-style sparse attention (v2) ----------------
// 4 waves, wave w owns q rows w*16..+15. Q fragments in REGISTERS (no qsb).
// Prologue (only when qt+1 > TOPK) reads Q from global (fp32, bit-identical scores).
// LDS 44.5KB -> 3 blocks/CU. K/V staging prefetched: global->reg issued right after
// the LDS-ready barrier, regs written to LDS at next loop top (latency hidden under
// compute). XCD swizzle groups each kv-head-group on one XCD for K/V L2 locality.
__global__ __launch_bounds__(256, 3) void attn_mfma_kernel(const float* __restrict__ q,
                                                           const unsigned short* __restrict__ kbp,
                                                           const unsigned short* __restrict__ vtp,
                                                           const float* __restrict__ kblk,
                                                           float* __restrict__ out) {
    __shared__ __align__(16) unsigned char smem[45568];
    unsigned short* ksb = (unsigned short*)smem;             // [64][136] bf16 K   17408B
    unsigned short* vsb = (unsigned short*)(smem + 17408);   // [128][72] bf16 V^T 18432B
    unsigned short* psb = (unsigned short*)(smem + 35840);   // 4 x [16][72] bf16 P 9216B
    unsigned int*  selm = (unsigned int*)(smem + 45056);     // [64]               256B
    // prologue aliases (dead before main loop; below 25344 < selm offset):
    float* kbf = (float*)smem;                               // [32][132] fp32 kblk 16896B
    float* bsc = (float*)(smem + 16896);                     // [64][33]  fp32 scores 8448B

    // XCD swizzle: grid fixed (32,32); XCD k gets flat ids {k,k+8,...} -> tiles
    // [128k,128(k+1)) -> heads [4k,4k+4) = one kv group per XCD.
    int bx = blockIdx.x, by = blockIdx.y;
    {
        const int flat = by * 32 + bx;
        const int swz = (flat & 7) * 128 + (flat >> 3);
        bx = swz & 31;
        by = swz >> 5;
    }
    const int qt = 31 - bx;
    const int h = by;
    const int kv = h >> 2;
    const int qbase = qt * 64;
    const int tid = threadIdx.x;
    const int lane = tid & 63;
    const int w = tid >> 6;
    const int m = lane & 15;
    const int quad = lane >> 4;
    const int wm = w * 16;

    // ---- selection ----
    unsigned int uni;
    if (qt + 1 > TOPK) {
        // stage kblk (fp32) into LDS
#pragma unroll
        for (int u = 0; u < 4; ++u) {
            const int idx = u * 1024 + tid * 4;
            const int b = idx >> 7, d = idx & 127;
            *(float4*)(kbf + b * 132 + d) =
                *(const float4*)(kblk + ((size_t)(kv * NBLK + b)) * HD + d);
        }
        __syncthreads();
        // block scores: q read straight from global (fp32, same FMA order as before)
        {
            float acc[4][2] = {};
            const int r0 = quad + 4 * w;
#pragma unroll 4
            for (int d = 0; d < 128; d += 4) {
                float4 qv[4], kb2[2];
#pragma unroll
                for (int i = 0; i < 4; ++i)
                    qv[i] = *(const float4*)(q + ((size_t)((qbase + r0 + 16 * i) * NH + h)) * HD + d);
#pragma unroll
                for (int j = 0; j < 2; ++j) kb2[j] = *(float4*)(kbf + (m + 16 * j) * 132 + d);
#pragma unroll
                for (int i = 0; i < 4; ++i)
#pragma unroll
                    for (int j = 0; j < 2; ++j) acc[i][j] += dot4f(qv[i], kb2[j]);
            }
#pragma unroll
            for (int i = 0; i < 4; ++i)
#pragma unroll
                for (int j = 0; j < 2; ++j) {
                    const int b = m + 16 * j;
                    if (b <= qt) bsc[(r0 + 16 * i) * 33 + b] = acc[i][j];
                }
        }
        __syncthreads();
        if (tid < 64) {
            unsigned int sel = 0;
            const float* br = bsc + tid * 33;
            for (int t2 = 0; t2 < TOPK; ++t2) {
                float best = -3.4e38f; int bi = 0;
                for (int b = 0; b <= qt; ++b)
                    if (!((sel >> b) & 1u) && br[b] > best) { best = br[b]; bi = b; }
                sel |= 1u << bi;
            }
            selm[tid] = sel;
        }
        __syncthreads();
        unsigned int u2 = 0;
        for (int i = 0; i < 64; ++i) u2 |= selm[i];
        uni = u2;
    } else {
        uni = (2u << qt) - 1;  // all allowed blocks selected (matches reference top-k + causal)
    }

    unsigned int selr[4];
#pragma unroll
    for (int r = 0; r < 4; ++r)
        selr[r] = (qt + 1 > TOPK) ? selm[wm + quad * 4 + r] : uni;

    // ---- Q fragments -> registers (bf16, same rounding as before) ----
    bfrag aq[4];
    {
        const float* qrow = q + ((size_t)((qbase + wm + m) * NH + h)) * HD;
#pragma unroll
        for (int ks = 0; ks < 4; ++ks) {
            const float4 f0 = *(const float4*)(qrow + ks * 32 + quad * 8);
            const float4 f1 = *(const float4*)(qrow + ks * 32 + quad * 8 + 4);
            bfrag a;
            a[0] = (short)f2b(f0.x); a[1] = (short)f2b(f0.y);
            a[2] = (short)f2b(f0.z); a[3] = (short)f2b(f0.w);
            a[4] = (short)f2b(f1.x); a[5] = (short)f2b(f1.y);
            a[6] = (short)f2b(f1.z); a[7] = (short)f2b(f1.w);
            aq[ks] = a;
        }
    }

    float m_run[4], l_run[4];
#pragma unroll
    for (int r = 0; r < 4; ++r) { m_run[r] = -3.0e38f; l_run[r] = 0.f; }
    ffrag o[8];
    const ffrag z = {0.f, 0.f, 0.f, 0.f};
#pragma unroll
    for (int n = 0; n < 8; ++n) o[n] = z;

    unsigned short* psw = psb + w * (16 * 72);

    // ---- staging addresses (per-u constants) ----
    // K: idx = u*256+tid -> r=idx>>4, dseg=(idx&15)*8 ; V: d=idx>>3, ks8=(idx&7)*8
    uint4 kreg[4], vreg[4];
    unsigned int rem = uni;
    if (rem) {
        const int b0 = __builtin_ctz(rem);
#pragma unroll
        for (int u = 0; u < 4; ++u) {
            const int idx = u * 256 + tid;
            kreg[u] = *(const uint4*)(kbp + (size_t)(b0 * 64 + (idx >> 4)) * 1024 + kv * 128 + (idx & 15) * 8);
        }
#pragma unroll
        for (int u = 0; u < 4; ++u) {
            const int idx = u * 256 + tid;
            vreg[u] = *(const uint4*)(vtp + (size_t)(kv * 128 + (idx >> 3)) * 2048 + b0 * 64 + (idx & 7) * 8);
        }
    }

    while (rem) {
        const int b = __builtin_ctz(rem);
        rem &= rem - 1;
        __syncthreads();  // prior compute done (also: prologue LDS dead on first iter)
        // regs -> LDS (compiler waits vmcnt for the in-flight loads)
#pragma unroll
        for (int u = 0; u < 4; ++u) {
            const int idx = u * 256 + tid;
            *(uint4*)(ksb + (idx >> 4) * 136 + (idx & 15) * 8) = kreg[u];
        }
#pragma unroll
        for (int u = 0; u < 4; ++u) {
            const int idx = u * 256 + tid;
            *(uint4*)(vsb + (idx >> 3) * 72 + (idx & 7) * 8) = vreg[u];
        }
        const bool hn = (rem != 0);
        const int bn = hn ? __builtin_ctz(rem) : 0;
        __syncthreads();  // LDS ready
        // prefetch next block into regs; latency hidden under compute below
        if (hn) {
#pragma unroll
            for (int u = 0; u < 4; ++u) {
                const int idx = u * 256 + tid;
                kreg[u] = *(const uint4*)(kbp + (size_t)(bn * 64 + (idx >> 4)) * 1024 + kv * 128 + (idx & 15) * 8);
            }
#pragma unroll
            for (int u = 0; u < 4; ++u) {
                const int idx = u * 256 + tid;
                vreg[u] = *(const uint4*)(vtp + (size_t)(kv * 128 + (idx >> 3)) * 2048 + bn * 64 + (idx & 7) * 8);
            }
        }

        // ---- QK^T: per wave 16 rows x 64 keys ----
        ffrag s[4];
#pragma unroll
        for (int j = 0; j < 4; ++j) s[j] = z;
        __builtin_amdgcn_s_setprio(1);
#pragma unroll
        for (int ks = 0; ks < 4; ++ks) {
#pragma unroll
            for (int j = 0; j < 4; ++j) {
                const bfrag bk = *(const bfrag*)(ksb + (j * 16 + m) * 136 + ks * 32 + quad * 8);
                s[j] = __builtin_amdgcn_mfma_f32_16x16x32_bf16(aq[ks], bk, s[j], 0, 0, 0);
            }
        }
        __builtin_amdgcn_s_setprio(0);

        // ---- mask + online softmax (register m/l, wave-exclusive rows) ----
        const bool diag = (b == qt);
        float a_r[4];
#pragma unroll
        for (int r = 0; r < 4; ++r) {
            const int rloc = quad * 4 + r;
            const int rtile = wm + rloc;
            const bool selb = (selr[r] >> b) & 1u;
            float sv[4];
#pragma unroll
            for (int j = 0; j < 4; ++j) {
                const int col = j * 16 + m;
                const bool valid = selb && (!diag || col <= rtile);
                sv[j] = valid ? s[j][r] * SCALE : -3.0e38f;
            }
            float t = fmaxf(fmaxf(sv[0], sv[1]), fmaxf(sv[2], sv[3]));
            t = fmaxf(t, __shfl_xor(t, 1));
            t = fmaxf(t, __shfl_xor(t, 2));
            t = fmaxf(t, __shfl_xor(t, 4));
            t = fmaxf(t, __shfl_xor(t, 8));
            const float mo = m_run[r];
            const float mn = fmaxf(mo, t);
            a_r[r] = __expf(mo - mn);
            float sum = 0.f;
#pragma unroll
            for (int j = 0; j < 4; ++j) {
                const float p = (sv[j] > -1.0e30f) ? __expf(sv[j] - mn) : 0.f;
                psw[rloc * 72 + j * 16 + m] = f2b(p);
                sum += p;
            }
            sum += __shfl_xor(sum, 1);
            sum += __shfl_xor(sum, 2);
            sum += __shfl_xor(sum, 4);
            sum += __shfl_xor(sum, 8);
            l_run[r] = l_run[r] * a_r[r] + sum;
            m_run[r] = mn;
        }
#pragma unroll
        for (int n = 0; n < 8; ++n)
#pragma unroll
            for (int r = 0; r < 4; ++r) o[n][r] *= a_r[r];

        // ---- PV: O(16x128) += P(16x64) @ V(64x128); P via wave-private LDS ----
        __builtin_amdgcn_s_setprio(1);
#pragma unroll
        for (int ks = 0; ks < 2; ++ks) {
            const bfrag pa = *(const bfrag*)(psw + m * 72 + ks * 32 + quad * 8);
#pragma unroll
            for (int n = 0; n < 8; ++n) {
                const bfrag bv = *(const bfrag*)(vsb + (n * 16 + m) * 72 + ks * 32 + quad * 8);
                o[n] = __builtin_amdgcn_mfma_f32_16x16x32_bf16(pa, bv, o[n], 0, 0, 0);
            }
        }
        __builtin_amdgcn_s_setprio(0);
    }

    // ---- epilogue ----
#pragma unroll
    for (int r = 0; r < 4; ++r) {
        const float inv = 1.f / l_run[r];
        float* op = out + ((size_t)((qbase + wm + quad * 4 + r) * NH + h)) * HD + m;
#pragma unroll
        for (int n = 0; n < 8; ++n) op[n * 16] = o[n][r] * inv;
    }
}

// ---------------- legacy VALU attention (fallback path) ----------------
__global__ __launch_bounds__(256) void attn_tile_kernel(const float* __restrict__ q,
                                                        const float* __restrict__ kptr,
                                                        const float* __restrict__ vptr,
                                                        const float* __restrict__ kblk,
                                                        float* __restrict__ out,
                                                        int kvstride) {
    __shared__ __align__(16) unsigned char smem[62464];
    unsigned short* ksb = (unsigned short*)smem;            // [64][136]
    unsigned short* vsb = (unsigned short*)(smem + 17408);  // [64][136]
    unsigned short* psb = (unsigned short*)(smem + 34816);  // [64][68]
    unsigned short* qsb = (unsigned short*)(smem + 43520);  // [64][136]
    float* mrow = (float*)(smem + 60928);
    float* lrow = (float*)(smem + 61184);
    float* arow = (float*)(smem + 61440);
    float* mnew = (float*)(smem + 61696);
    unsigned int* selm = (unsigned int*)(smem + 61952);
    float* qf  = (float*)smem;             // [64][132]
    float* kbf = (float*)(smem + 33792);   // [32][132]
    float* bsc = (float*)(smem + 50688);   // [64][33]

    const int qt = 31 - blockIdx.x;
    const int h = blockIdx.y;
    const int kv = h >> 2;
    const int qbase = qt * 64;
    const int tid = threadIdx.x;
    const int lane = tid & 63;
    const int w = tid >> 6;
    const int kl = lane & 15;
    const int ql = lane >> 4;

#pragma unroll
    for (int u = 0; u < 8; ++u) {
        const int idx = u * 1024 + tid * 4;
        const int qi = idx >> 7, d = idx & 127;
        *(float4*)(qf + qi * 132 + d) =
            *(const float4*)(q + ((size_t)((qbase + qi) * NH + h)) * HD + d);
    }
#pragma unroll
    for (int u = 0; u < 4; ++u) {
        const int idx = u * 1024 + tid * 4;
        const int b = idx >> 7, d = idx & 127;
        *(float4*)(kbf + b * 132 + d) =
            *(const float4*)(kblk + ((size_t)(kv * NBLK + b)) * HD + d);
    }
    __syncthreads();

    {
        float acc[4][2] = {};
#pragma unroll 4
        for (int d = 0; d < 128; d += 4) {
            float4 qv[4], kb2[2];
#pragma unroll
            for (int i = 0; i < 4; ++i) qv[i] = *(float4*)(qf + (ql + 4 * w + 16 * i) * 132 + d);
#pragma unroll
            for (int j = 0; j < 2; ++j) kb2[j] = *(float4*)(kbf + (kl + 16 * j) * 132 + d);
#pragma unroll
            for (int i = 0; i < 4; ++i)
#pragma unroll
                for (int j = 0; j < 2; ++j) acc[i][j] += dot4f(qv[i], kb2[j]);
        }
#pragma unroll
        for (int i = 0; i < 4; ++i)
#pragma unroll
            for (int j = 0; j < 2; ++j) {
                const int b = kl + 16 * j;
                if (b <= qt) bsc[(ql + 4 * w + 16 * i) * 33 + b] = acc[i][j];
            }
    }
    __syncthreads();

    if (tid < 64) {
        const int ns = (qt + 1 < TOPK) ? qt + 1 : TOPK;
        unsigned int sel = 0;
        const float* br = bsc + tid * 33;
        for (int t = 0; t < ns; ++t) {
            float best = -3.4e38f; int bi = 0;
            for (int b = 0; b <= qt; ++b)
                if (!((sel >> b) & 1u) && br[b] > best) { best = br[b]; bi = b; }
            sel |= 1u << bi;
        }
        selm[tid] = sel;
        mrow[tid] = -3.0e38f;
        lrow[tid] = 0.f;
    }
    __syncthreads();

    unsigned int uni = 0;
    {
        float tmp[32];
#pragma unroll
        for (int u = 0; u < 8; ++u) {
            const int idx = u * 1024 + tid * 4;
            *(float4*)(tmp + u * 4) = *(float4*)(qf + (idx >> 7) * 132 + (idx & 127));
        }
        for (int i = 0; i < 64; ++i) uni |= selm[i];
#pragma unroll
        for (int u = 0; u < 8; ++u) {
            const int idx = u * 1024 + tid * 4;
            const int qi = idx >> 7, d = idx & 127;
            ushort4 qu;
            qu.x = f2b(tmp[u * 4 + 0]); qu.y = f2b(tmp[u * 4 + 1]);
            qu.z = f2b(tmp[u * 4 + 2]); qu.w = f2b(tmp[u * 4 + 3]);
            *(ushort4*)(qsb + qi * 136 + d) = qu;
        }
    }
    __syncthreads();

    const int qi_r[4] = {ql + 4 * w, ql + 4 * w + 16, ql + 4 * w + 32, ql + 4 * w + 48};
    unsigned int selq[4];
#pragma unroll
    for (int i = 0; i < 4; ++i) selq[i] = selm[qi_r[i]];

    float O[4][8] = {};

    for (int b = 0; b <= qt; ++b) {
        if (!((uni >> b) & 1u)) continue;
        __syncthreads();
#pragma unroll
        for (int u = 0; u < 8; ++u) {
            const int idx = u * 1024 + tid * 4;
            const int r = idx >> 7, d = idx & 127;
            const size_t gof = (size_t)(b * 64 + r) * kvstride + kv * HD + d;
            const float4 k4 = *(const float4*)(kptr + gof);
            const float4 v4 = *(const float4*)(vptr + gof);
            ushort4 ku, vu;
            ku.x = f2b(k4.x); ku.y = f2b(k4.y); ku.z = f2b(k4.z); ku.w = f2b(k4.w);
            vu.x = f2b(v4.x); vu.y = f2b(v4.y); vu.z = f2b(v4.z); vu.w = f2b(v4.w);
            *(ushort4*)(ksb + r * 136 + d) = ku;
            *(ushort4*)(vsb + r * 136 + d) = vu;
        }
        __syncthreads();

        float S[4][4] = {};
#pragma unroll 4
        for (int d = 0; d < 128; d += 4) {
            float qv[4][4], kk4[4][4];
#pragma unroll
            for (int i = 0; i < 4; ++i) unpack4(*(uint2*)(qsb + qi_r[i] * 136 + d), qv[i]);
#pragma unroll
            for (int j = 0; j < 4; ++j) unpack4(*(uint2*)(ksb + (kl + 16 * j) * 136 + d), kk4[j]);
#pragma unroll
            for (int i = 0; i < 4; ++i)
#pragma unroll
                for (int j = 0; j < 4; ++j)
#pragma unroll
                    for (int e = 0; e < 4; ++e) S[i][j] += qv[i][e] * kk4[j][e];
        }

        const bool diag = (b == qt);
        float tm[4];
#pragma unroll
        for (int i = 0; i < 4; ++i) {
            const bool selb = (selq[i] >> b) & 1u;
#pragma unroll
            for (int j = 0; j < 4; ++j) {
                const int kj = kl + 16 * j;
                const bool valid = selb && (!diag || kj <= qi_r[i]);
                S[i][j] = valid ? S[i][j] * SCALE : -3.0e38f;
            }
            float t = fmaxf(fmaxf(S[i][0], S[i][1]), fmaxf(S[i][2], S[i][3]));
            t = fmaxf(t, __shfl_xor(t, 1));
            t = fmaxf(t, __shfl_xor(t, 2));
            t = fmaxf(t, __shfl_xor(t, 4));
            t = fmaxf(t, __shfl_xor(t, 8));
            tm[i] = t;
        }
        if (kl == 0) {
#pragma unroll
            for (int i = 0; i < 4; ++i) {
                const float mo = mrow[qi_r[i]];
                const float mn = fmaxf(mo, tm[i]);
                mrow[qi_r[i]] = mn;
                mnew[qi_r[i]] = mn;
                arow[qi_r[i]] = __expf(mo - mn);
            }
        }
        __syncthreads();

        float tl[4];
#pragma unroll
        for (int i = 0; i < 4; ++i) {
            const float mn = mnew[qi_r[i]];
            float sum = 0.f;
#pragma unroll
            for (int j = 0; j < 4; ++j) {
                const float p = (S[i][j] > -1.0e30f) ? __expf(S[i][j] - mn) : 0.f;
                psb[qi_r[i] * 68 + kl + 16 * j] = f2b(p);
                sum += p;
            }
            sum += __shfl_xor(sum, 1);
            sum += __shfl_xor(sum, 2);
            sum += __shfl_xor(sum, 4);
            sum += __shfl_xor(sum, 8);
            tl[i] = sum;
        }
        if (kl == 0) {
#pragma unroll
            for (int i = 0; i < 4; ++i)
                lrow[qi_r[i]] = lrow[qi_r[i]] * arow[qi_r[i]] + tl[i];
        }
#pragma unroll
        for (int i = 0; i < 4; ++i) {
            const float a = arow[qi_r[i]];
#pragma unroll
            for (int e = 0; e < 8; ++e) O[i][e] *= a;
        }
        __syncthreads();

#pragma unroll 4
        for (int kj = 0; kj < 64; ++kj) {
            float p[4];
#pragma unroll
            for (int i = 0; i < 4; ++i) {
                unsigned short us = psb[qi_r[i] * 68 + kj];
                p[i] = bitsf(((unsigned int)us) << 16);
            }
            float vv[8];
            unpack8(*(uint4*)(vsb + kj * 136 + kl * 8), vv);
#pragma unroll
            for (int i = 0; i < 4; ++i)
#pragma unroll
                for (int e = 0; e < 8; ++e) O[i][e] += p[i] * vv[e];
        }
    }
    __syncthreads();

#pragma unroll
    for (int i = 0; i < 4; ++i) {
        const float inv = 1.f / lrow[qi_r[i]];
        float4 o0, o1;
        o0.x = O[i][0] * inv; o0.y = O[i][1] * inv; o0.z = O[i][2] * inv; o0.w = O[i][3] * inv;
        o1.x = O[i][4] * inv; o1.y = O[i][5] * inv; o1.z = O[i][6] * inv; o1.w = O[i][7] * inv;
        float* op = out + ((size_t)((qbase + qi_r[i]) * NH + h)) * HD + kl * 8;
        *(float4*)op = o0;
        *(float4*)(op + 4) = o1;
    }
}

// ---------------- launch ----------------
extern "C" void kernel_launch(void* const* d_in, const int* in_sizes, int n_in,
                              void* d_out, int out_size, void* d_ws, size_t ws_size,
                              hipStream_t stream) {
    const float* x    = (const float*)d_in[0];
    const float* cosb = (const float*)d_in[1];
    const float* sinb = (const float*)d_in[2];
    const float* wq   = (const float*)d_in[3];
    const float* wk   = (const float*)d_in[4];
    const float* wv   = (const float*)d_in[5];
    const float* wo   = (const float*)d_in[6];

    unsigned char* ws = (unsigned char*)d_ws;
    const dim3 t256(256);

    const size_t MAIN_REQ = 184680448ull;  // 176 MB layout below
    if (ws_size >= MAIN_REQ) {
        // ---- main path: MFMA GEMMs + MFMA attention ----
        float*          qf     = (float*)(ws);                       // 32 MB
        float*          kvf    = (float*)(ws + 33554432ull);         // 16 MB (k cols 0..1023, v 1024..2047)
        float*          kblk   = (float*)(ws + 50331648ull);         // 128 KB
        unsigned short* x_hi   = (unsigned short*)(ws + 50462720ull); // 16 MB
        unsigned short* x_lo   = (unsigned short*)(ws + 67239936ull); // 16 MB
        float*          attn   = (float*)(ws + 50462720ull);          // 32 MB (aliases x_hi+x_lo; x dead)
        unsigned short* wqT_hi = (unsigned short*)(ws + 84017152ull); // 32 MB (later woT_hi)
        unsigned short* wqT_lo = (unsigned short*)(ws + 117571584ull);// 32 MB (later attn_bf)
        unsigned short* kvT_hi = (unsigned short*)(ws + 151126016ull);// 16 MB (later kb16)
        unsigned short* kvT_lo = (unsigned short*)(ws + 167903232ull);// 16 MB (later vt)
        unsigned short* woT_hi = wqT_hi;
        unsigned short* attnbf = wqT_lo;
        unsigned short* kb16   = kvT_hi;  // 4 MB bf16 K  [SEQ][1024] (kvT dead after kv gemm)
        unsigned short* vtb    = kvT_lo;  // 4 MB bf16 V^T [1024][SEQ]

        // x -> hi/lo bf16
        conv_hilo<<<SEQ * DIM / 4 / 256, t256, 0, stream>>>(x, x_hi, x_lo);
        // weight transposes (N x K, K=4096)
        transpose_conv<<<dim3(DIM / 32, DIM / 32), t256, 0, stream>>>(wq, wqT_hi, wqT_lo, DIM, DIM, 0);
        transpose_conv<<<dim3(KVDIM / 32, DIM / 32), t256, 0, stream>>>(wk, kvT_hi, kvT_lo, DIM, KVDIM, 0);
        transpose_conv<<<dim3(KVDIM / 32, DIM / 32), t256, 0, stream>>>(wv, kvT_hi, kvT_lo, DIM, KVDIM, KVDIM);

        // q = x @ wq (split, ~fp32)
        hipLaunchKernelGGL((mfma_gemm<true>), dim3(DIM / 128, SEQ / 128), t256, 0, stream,
                           x_hi, x_lo, wqT_hi, wqT_lo, qf, SEQ, DIM, DIM);
        // [k|v] = x @ [wk|wv] (split)
        hipLaunchKernelGGL((mfma_gemm<true>), dim3(2 * KVDIM / 128, SEQ / 128), t256, 0, stream,
                           x_hi, x_lo, kvT_hi, kvT_lo, kvf, SEQ, 2 * KVDIM, DIM);
        // wo transpose into freed wqT_hi region
        transpose_conv<<<dim3(DIM / 32, DIM / 32), t256, 0, stream>>>(wo, woT_hi, nullptr, DIM, DIM, 0);

        rope_kernel<<<(SEQ * NH * 64) / 256, t256, 0, stream>>>(qf, cosb, sinb, NH, NH * HD);
        rope_kernel<<<(SEQ * NKV * 64) / 256, t256, 0, stream>>>(kvf, cosb, sinb, NKV, 2 * KVDIM);
        blkmean_kernel<<<(NKV * NBLK * HD) / 256, t256, 0, stream>>>(kvf, kblk, 2 * KVDIM);

        // precompute bf16 K (row-major) and bf16 V transposed (kvT regions are dead now)
        kconv_kernel<<<(SEQ * KVDIM / 4) / 256, t256, 0, stream>>>(kvf, kb16);
        vtrans_kernel<<<dim3(SEQ / 64, KVDIM / 64), t256, 0, stream>>>(kvf, vtb);

        attn_mfma_kernel<<<dim3(NBLK, NH), t256, 0, stream>>>(qf, kb16, vtb, kblk, attn);

        // attn -> bf16, then out = attn @ wo (plain bf16)
        conv_hilo<<<SEQ * DIM / 4 / 256, t256, 0, stream>>>(attn, attnbf, nullptr);
        hipLaunchKernelGGL((mfma_gemm<false>), dim3(DIM / 128, SEQ / 128), t256, 0, stream,
                           attnbf, nullptr, woT_hi, nullptr, (float*)d_out, SEQ, DIM, DIM);
    } else {
        // ---- fallback: R3 fp32 pipeline (76 MB) ----
        float* qf   = (float*)ws;
        float* kf   = qf + (size_t)SEQ * DIM;
        float* vf   = kf + (size_t)SEQ * KVDIM;
        float* kblk = vf + (size_t)SEQ * KVDIM;
        float* attn = kblk + (size_t)NKV * NBLK * HD;

        gemm_kernel<<<dim3(DIM / 64, SEQ / 64), t256, 0, stream>>>(x, wq, qf, SEQ, DIM, DIM);
        gemm_kernel<<<dim3(KVDIM / 64, SEQ / 64), t256, 0, stream>>>(x, wk, kf, SEQ, KVDIM, DIM);
        gemm_kernel<<<dim3(KVDIM / 64, SEQ / 64), t256, 0, stream>>>(x, wv, vf, SEQ, KVDIM, DIM);
        rope_kernel<<<(SEQ * NH * 64) / 256, t256, 0, stream>>>(qf, cosb, sinb, NH, NH * HD);
        rope_kernel<<<(SEQ * NKV * 64) / 256, t256, 0, stream>>>(kf, cosb, sinb, NKV, KVDIM);
        blkmean_kernel<<<(NKV * NBLK * HD) / 256, t256, 0, stream>>>(kf, kblk, KVDIM);
        attn_tile_kernel<<<dim3(NBLK, NH), t256, 0, stream>>>(qf, kf, vf, kblk, attn, KVDIM);
        gemm_kernel<<<dim3(DIM / 64, SEQ / 64), t256, 0, stream>>>(attn, wo, (float*)d_out, SEQ, DIM, DIM);
    }
}

// Round 5
// 887.204 us; speedup vs baseline: 1.1044x; 1.1044x over previous
//
#include <hip/hip_runtime.h>
#include <hip/hip_bf16.h>
#include <math.h>

#define SEQ 2048
#define DIM 4096
#define NH 32
#define HD 128
#define NKV 8
#define NREP 4
#define BLOCK 64
#define NBLK 32
#define TOPK 8
#define KVDIM (NKV * HD)   // 1024
#define SCALE 0.08838834764831845f

// ---------------- bf16 helpers ----------------
__device__ inline unsigned short f2b(float f) {
    __hip_bfloat16 h = __float2bfloat16(f);
    return *reinterpret_cast<unsigned short*>(&h);
}
__device__ inline float bitsf(unsigned int u) {
    union { float f; unsigned int i; } x; x.i = u; return x.f;
}
__device__ inline float b2f(unsigned short us) { return bitsf(((unsigned int)us) << 16); }
__device__ inline void unpack2(unsigned int w0, float* o) {
    o[0] = bitsf(w0 << 16);
    o[1] = bitsf(w0 & 0xffff0000u);
}
__device__ inline void unpack4(uint2 w, float* o) { unpack2(w.x, o); unpack2(w.y, o + 2); }
__device__ inline void unpack8(uint4 w, float* o) {
    unpack2(w.x, o); unpack2(w.y, o + 2); unpack2(w.z, o + 4); unpack2(w.w, o + 6);
}
__device__ inline float dot4f(float4 a, float4 b) {
    return a.x * b.x + a.y * b.y + a.z * b.z + a.w * b.w;
}

// ---------------- MFMA GEMM: C(MxN) = A(MxK) @ Bt(NxK)^T, bf16 in / fp32 out -------
typedef __attribute__((ext_vector_type(8))) short bfrag;
typedef __attribute__((ext_vector_type(4))) float ffrag;

__device__ __forceinline__ void gl_lds16(const void* g, void* l) {
    __builtin_amdgcn_global_load_lds((const __attribute__((address_space(1))) void*)g,
                                     (__attribute__((address_space(3))) void*)l, 16, 0, 0);
}

template <bool SPLIT>
__global__ __launch_bounds__(256) void mfma_gemm(const unsigned short* __restrict__ Ah,
                                                 const unsigned short* __restrict__ Al,
                                                 const unsigned short* __restrict__ Bh,
                                                 const unsigned short* __restrict__ Bl,
                                                 float* __restrict__ C,
                                                 int M, int N, int K) {
    __shared__ short As[(SPLIT ? 2 : 1) * 4096];  // [hi(,lo)][128][32]
    __shared__ short Bs[(SPLIT ? 2 : 1) * 4096];

    const int tid = threadIdx.x;
    const int lane = tid & 63;
    const int w = tid >> 6;
    const int wm = (w >> 1) * 64;
    const int wn = (w & 1) * 64;
    const int m = lane & 15;
    const int quad = lane >> 4;

    // XCD-aware bijective swizzle (nwg % 8 == 0 for all grids used here)
    int bx = blockIdx.x, by = blockIdx.y;
    {
        const int nwg = gridDim.x * gridDim.y;
        if ((nwg & 7) == 0) {
            const int flat = by * gridDim.x + bx;
            const int nper = nwg >> 3;
            const int swz = (flat & 7) * nper + (flat >> 3);
            bx = swz % gridDim.x;
            by = swz / gridDim.x;
        }
    }
    const int bm = by * 128;
    const int bn = bx * 128;

    const int r0 = tid >> 2;
    const int c0 = (tid & 3) * 8;
    const size_t aoff0 = (size_t)(bm + r0) * K + c0;
    const size_t aoff1 = (size_t)(bm + r0 + 64) * K + c0;
    const size_t boff0 = (size_t)(bn + r0) * K + c0;
    const size_t boff1 = (size_t)(bn + r0 + 64) * K + c0;

    ffrag acc[4][4];
    const ffrag z = {0.f, 0.f, 0.f, 0.f};
#pragma unroll
    for (int i = 0; i < 4; ++i)
#pragma unroll
        for (int j = 0; j < 4; ++j) acc[i][j] = z;

    for (int kt = 0; kt < K; kt += 32) {
        __syncthreads();
        gl_lds16(Ah + aoff0 + kt, As + tid * 8);
        gl_lds16(Ah + aoff1 + kt, As + 2048 + tid * 8);
        gl_lds16(Bh + boff0 + kt, Bs + tid * 8);
        gl_lds16(Bh + boff1 + kt, Bs + 2048 + tid * 8);
        if constexpr (SPLIT) {
            gl_lds16(Al + aoff0 + kt, As + 4096 + tid * 8);
            gl_lds16(Al + aoff1 + kt, As + 6144 + tid * 8);
            gl_lds16(Bl + boff0 + kt, Bs + 4096 + tid * 8);
            gl_lds16(Bl + boff1 + kt, Bs + 6144 + tid * 8);
        }
        __syncthreads();

        bfrag ah[4], bh[4];
#pragma unroll
        for (int i = 0; i < 4; ++i)
            ah[i] = *(const bfrag*)(As + (wm + i * 16 + m) * 32 + quad * 8);
#pragma unroll
        for (int j = 0; j < 4; ++j)
            bh[j] = *(const bfrag*)(Bs + (wn + j * 16 + m) * 32 + quad * 8);
        if constexpr (SPLIT) {
            bfrag al[4], bl[4];
#pragma unroll
            for (int i = 0; i < 4; ++i)
                al[i] = *(const bfrag*)(As + 4096 + (wm + i * 16 + m) * 32 + quad * 8);
#pragma unroll
            for (int j = 0; j < 4; ++j)
                bl[j] = *(const bfrag*)(Bs + 4096 + (wn + j * 16 + m) * 32 + quad * 8);
#pragma unroll
            for (int i = 0; i < 4; ++i)
#pragma unroll
                for (int j = 0; j < 4; ++j) {
                    acc[i][j] = __builtin_amdgcn_mfma_f32_16x16x32_bf16(ah[i], bh[j], acc[i][j], 0, 0, 0);
                    acc[i][j] = __builtin_amdgcn_mfma_f32_16x16x32_bf16(ah[i], bl[j], acc[i][j], 0, 0, 0);
                    acc[i][j] = __builtin_amdgcn_mfma_f32_16x16x32_bf16(al[i], bh[j], acc[i][j], 0, 0, 0);
                }
        } else {
#pragma unroll
            for (int i = 0; i < 4; ++i)
#pragma unroll
                for (int j = 0; j < 4; ++j)
                    acc[i][j] = __builtin_amdgcn_mfma_f32_16x16x32_bf16(ah[i], bh[j], acc[i][j], 0, 0, 0);
        }
    }

#pragma unroll
    for (int i = 0; i < 4; ++i)
#pragma unroll
        for (int j = 0; j < 4; ++j)
#pragma unroll
            for (int r = 0; r < 4; ++r)
                C[(size_t)(bm + wm + i * 16 + quad * 4 + r) * N + bn + wn + j * 16 + m] =
                    acc[i][j][r];
}

// ---------------- transpose + bf16 split: W(KxN fp32) -> T(NxK bf16 hi[,lo]) --------
__global__ __launch_bounds__(256) void transpose_conv(const float* __restrict__ W,
                                                      unsigned short* __restrict__ Th,
                                                      unsigned short* __restrict__ Tl,
                                                      int K, int N, int rowoff) {
    __shared__ float tile[32][36];
    const int k0 = blockIdx.y * 32, n0 = blockIdx.x * 32;
    const int t = threadIdx.x;
    const int r = t >> 3, c4 = (t & 7) * 4;
    *(float4*)&tile[r][c4] = *(const float4*)(W + (size_t)(k0 + r) * N + n0 + c4);
    __syncthreads();
    float v0 = tile[c4 + 0][r], v1 = tile[c4 + 1][r], v2 = tile[c4 + 2][r], v3 = tile[c4 + 3][r];
    ushort4 h;
    h.x = f2b(v0); h.y = f2b(v1); h.z = f2b(v2); h.w = f2b(v3);
    const size_t ooff = (size_t)(rowoff + n0 + r) * K + k0 + c4;
    *(ushort4*)(Th + ooff) = h;
    if (Tl) {
        ushort4 l;
        l.x = f2b(v0 - b2f(h.x)); l.y = f2b(v1 - b2f(h.y));
        l.z = f2b(v2 - b2f(h.z)); l.w = f2b(v3 - b2f(h.w));
        *(ushort4*)(Tl + ooff) = l;
    }
}

// ---------------- elementwise fp32 -> bf16 hi (+lo) ----------------
__global__ void conv_hilo(const float* __restrict__ X, unsigned short* __restrict__ H,
                          unsigned short* __restrict__ L) {
    const int i = (blockIdx.x * blockDim.x + threadIdx.x) * 4;
    const float4 x = *(const float4*)(X + i);
    ushort4 h;
    h.x = f2b(x.x); h.y = f2b(x.y); h.z = f2b(x.z); h.w = f2b(x.w);
    *(ushort4*)(H + i) = h;
    if (L) {
        ushort4 l;
        l.x = f2b(x.x - b2f(h.x)); l.y = f2b(x.y - b2f(h.y));
        l.z = f2b(x.z - b2f(h.z)); l.w = f2b(x.w - b2f(h.w));
        *(ushort4*)(L + i) = l;
    }
}

// ---------------- K half of kvf -> bf16 row-major [SEQ][KVDIM] ----------------
__global__ void kconv_kernel(const float* __restrict__ kvf, unsigned short* __restrict__ kb) {
    const int i = (blockIdx.x * blockDim.x + threadIdx.x) * 4;
    const int s = i >> 10, c = i & 1023;
    const float4 x = *(const float4*)(kvf + (size_t)s * 2048 + c);
    ushort4 h;
    h.x = f2b(x.x); h.y = f2b(x.y); h.z = f2b(x.z); h.w = f2b(x.w);
    *(ushort4*)(kb + (size_t)s * 1024 + c) = h;
}

// ---------------- V half of kvf -> bf16 TRANSPOSED [KVDIM][SEQ] ----------------
__global__ __launch_bounds__(256) void vtrans_kernel(const float* __restrict__ kvf,
                                                     unsigned short* __restrict__ vt) {
    __shared__ unsigned short tile[64][72];
    const int s0 = blockIdx.x * 64;
    const int c0 = blockIdx.y * 64;
    const int t = threadIdx.x;
    const int r = t >> 4;            // 0..15
    const int c4 = (t & 15) * 4;     // 0..60
#pragma unroll
    for (int u = 0; u < 4; ++u) {
        const float4 x = *(const float4*)(kvf + (size_t)(s0 + u * 16 + r) * 2048 + 1024 + c0 + c4);
        ushort4 hh;
        hh.x = f2b(x.x); hh.y = f2b(x.y); hh.z = f2b(x.z); hh.w = f2b(x.w);
        *(ushort4*)(&tile[u * 16 + r][c4]) = hh;
    }
    __syncthreads();
    const int cc = t >> 2;           // 0..63
    const int sg = (t & 3) * 16;     // 0,16,32,48
    union { unsigned short s[16]; uint4 v[2]; } bb;
#pragma unroll
    for (int i = 0; i < 16; ++i) bb.s[i] = tile[sg + i][cc];
    unsigned short* op = vt + (size_t)(c0 + cc) * 2048 + s0 + sg;
    *(uint4*)op = bb.v[0];
    *(uint4*)(op + 8) = bb.v[1];
}

// ---------------- fallback fp32 GEMM (R2/R3 proven) ----------------
__global__ __launch_bounds__(256) void gemm_kernel(const float* __restrict__ A,
                                                   const float* __restrict__ B,
                                                   float* __restrict__ C,
                                                   int M, int N, int K) {
    __shared__ __align__(16) float As[16][68];
    __shared__ __align__(16) float Bs[16][68];

    const int tid = threadIdx.x;
    const int bm = blockIdx.y * 64;
    const int bn = blockIdx.x * 64;
    const int tm = (tid >> 4) * 4;
    const int tn = (tid & 15) * 4;

    float acc[4][4] = {};

    for (int k0 = 0; k0 < K; k0 += 16) {
        {
            const int mm = tid >> 2;
            const int kk = (tid & 3) * 4;
            const float* ap = A + (size_t)(bm + mm) * K + k0 + kk;
            const float4 a4 = *reinterpret_cast<const float4*>(ap);
            As[kk + 0][mm] = a4.x;
            As[kk + 1][mm] = a4.y;
            As[kk + 2][mm] = a4.z;
            As[kk + 3][mm] = a4.w;
        }
        {
            const int kk = tid >> 4;
            const int n = (tid & 15) * 4;
            const float* bp = B + (size_t)(k0 + kk) * N + bn + n;
            *reinterpret_cast<float4*>(&Bs[kk][n]) = *reinterpret_cast<const float4*>(bp);
        }
        __syncthreads();
#pragma unroll
        for (int kk = 0; kk < 16; ++kk) {
            const float4 a4 = *reinterpret_cast<const float4*>(&As[kk][tm]);
            const float4 b4 = *reinterpret_cast<const float4*>(&Bs[kk][tn]);
            const float av[4] = {a4.x, a4.y, a4.z, a4.w};
            const float bv[4] = {b4.x, b4.y, b4.z, b4.w};
#pragma unroll
            for (int i = 0; i < 4; ++i)
#pragma unroll
                for (int j = 0; j < 4; ++j) acc[i][j] += av[i] * bv[j];
        }
        __syncthreads();
    }
#pragma unroll
    for (int i = 0; i < 4; ++i)
#pragma unroll
        for (int j = 0; j < 4; ++j)
            C[(size_t)(bm + tm + i) * N + bn + tn + j] = acc[i][j];
}

// ---------------- RoPE (in place, fp32 buffer; row stride param) ----------------
__global__ void rope_kernel(float* __restrict__ x, const float* __restrict__ cosb,
                            const float* __restrict__ sinb, int nh, int stride) {
    const int idx = blockIdx.x * blockDim.x + threadIdx.x;
    const int i = idx & 63;
    const int h = (idx >> 6) % nh;
    const int pos = idx / (64 * nh);
    const float c = cosb[pos * 64 + i];
    const float s = sinb[pos * 64 + i];
    float* p = x + (size_t)pos * stride + h * HD + 2 * i;
    const float x0 = p[0], x1 = p[1];
    p[0] = x0 * c - x1 * s;
    p[1] = x0 * s + x1 * c;
}

// ---------------- Block means of K ----------------
__global__ void blkmean_kernel(const float* __restrict__ k, float* __restrict__ kblk,
                               int stride) {
    const int idx = blockIdx.x * blockDim.x + threadIdx.x;
    const int d = idx & 127;
    const int blk = (idx >> 7) & 31;
    const int kv = idx >> 12;
    float s = 0.f;
#pragma unroll 8
    for (int r = 0; r < BLOCK; ++r)
        s += k[(size_t)(blk * BLOCK + r) * stride + kv * HD + d];
    kblk[idx] = s * (1.f / 64.f);
}

// ---------------- MFMA flash-style sparse attention (v3) ----------------
// 4 waves, wave w owns q rows w*16..+15; Q fragments + softmax m/l in registers.
// K/V staged via global_load_lds DMA into UNPADDED LDS tiles with XOR swizzle
// (byte ^= (row&7)<<4) applied on BOTH sides: inverse-swizzled per-lane global
// source addresses at staging (linear LDS dest), swizzled ds_read on use — bank
// distribution identical to the old padded layout (2-way, free). No staging VGPRs,
// no launch_bounds cap -> no spill. LDS 42.2KB -> 3 blocks/CU.
__global__ __launch_bounds__(256) void attn_mfma_kernel(const float* __restrict__ q,
                                                        const unsigned short* __restrict__ kbp,
                                                        const unsigned short* __restrict__ vtp,
                                                        const float* __restrict__ kblk,
                                                        float* __restrict__ out) {
    __shared__ __align__(16) unsigned char smem[42240];
    unsigned short* ksb = (unsigned short*)smem;             // [64][128] bf16 K (swz) 16384B
    unsigned short* vsb = (unsigned short*)(smem + 16384);   // [128][64] bf16 V^T (swz) 16384B
    unsigned short* psb = (unsigned short*)(smem + 32768);   // 4 x [16][72] bf16 P   9216B
    unsigned int*  selm = (unsigned int*)(smem + 41984);     // [64]                   256B
    // prologue aliases (dead before main loop):
    float* kbf = (float*)smem;                               // [32][132] fp32 kblk 16896B
    float* bsc = (float*)(smem + 16896);                     // [64][33]  fp32 scores 8448B

    // XCD swizzle: grid fixed (32,32); XCD k gets flat ids {k,k+8,...} -> heads
    // [4k,4k+4) = one kv group per XCD (K/V L2 locality).
    int bx = blockIdx.x, by = blockIdx.y;
    {
        const int flat = by * 32 + bx;
        const int swz = (flat & 7) * 128 + (flat >> 3);
        bx = swz & 31;
        by = swz >> 5;
    }
    const int qt = 31 - bx;
    const int h = by;
    const int kv = h >> 2;
    const int qbase = qt * 64;
    const int tid = threadIdx.x;
    const int lane = tid & 63;
    const int w = tid >> 6;
    const int m = lane & 15;
    const int quad = lane >> 4;
    const int wm = w * 16;

    // ---- selection ----
    unsigned int uni;
    if (qt + 1 > TOPK) {
        // stage kblk (fp32) into LDS
#pragma unroll
        for (int u = 0; u < 4; ++u) {
            const int idx = u * 1024 + tid * 4;
            const int b = idx >> 7, d = idx & 127;
            *(float4*)(kbf + b * 132 + d) =
                *(const float4*)(kblk + ((size_t)(kv * NBLK + b)) * HD + d);
        }
        __syncthreads();
        // block scores: q read straight from global (fp32, same FMA order as before)
        {
            float acc[4][2] = {};
            const int r0 = quad + 4 * w;
#pragma unroll 4
            for (int d = 0; d < 128; d += 4) {
                float4 qv[4], kb2[2];
#pragma unroll
                for (int i = 0; i < 4; ++i)
                    qv[i] = *(const float4*)(q + ((size_t)((qbase + r0 + 16 * i) * NH + h)) * HD + d);
#pragma unroll
                for (int j = 0; j < 2; ++j) kb2[j] = *(float4*)(kbf + (m + 16 * j) * 132 + d);
#pragma unroll
                for (int i = 0; i < 4; ++i)
#pragma unroll
                    for (int j = 0; j < 2; ++j) acc[i][j] += dot4f(qv[i], kb2[j]);
            }
#pragma unroll
            for (int i = 0; i < 4; ++i)
#pragma unroll
                for (int j = 0; j < 2; ++j) {
                    const int b = m + 16 * j;
                    if (b <= qt) bsc[(r0 + 16 * i) * 33 + b] = acc[i][j];
                }
        }
        __syncthreads();
        if (tid < 64) {
            unsigned int sel = 0;
            const float* br = bsc + tid * 33;
            for (int t2 = 0; t2 < TOPK; ++t2) {
                float best = -3.4e38f; int bi = 0;
                for (int b = 0; b <= qt; ++b)
                    if (!((sel >> b) & 1u) && br[b] > best) { best = br[b]; bi = b; }
                sel |= 1u << bi;
            }
            selm[tid] = sel;
        }
        __syncthreads();
        unsigned int u2 = 0;
        for (int i = 0; i < 64; ++i) u2 |= selm[i];
        uni = u2;
    } else {
        uni = (2u << qt) - 1;  // all allowed blocks selected (matches reference top-k + causal)
    }

    unsigned int selr[4];
#pragma unroll
    for (int r = 0; r < 4; ++r)
        selr[r] = (qt + 1 > TOPK) ? selm[wm + quad * 4 + r] : uni;

    // ---- Q fragments -> registers (bf16, same rounding as before) ----
    bfrag aq[4];
    {
        const float* qrow = q + ((size_t)((qbase + wm + m) * NH + h)) * HD;
#pragma unroll
        for (int ks = 0; ks < 4; ++ks) {
            const float4 f0 = *(const float4*)(qrow + ks * 32 + quad * 8);
            const float4 f1 = *(const float4*)(qrow + ks * 32 + quad * 8 + 4);
            bfrag a;
            a[0] = (short)f2b(f0.x); a[1] = (short)f2b(f0.y);
            a[2] = (short)f2b(f0.z); a[3] = (short)f2b(f0.w);
            a[4] = (short)f2b(f1.x); a[5] = (short)f2b(f1.y);
            a[6] = (short)f2b(f1.z); a[7] = (short)f2b(f1.w);
            aq[ks] = a;
        }
    }

    float m_run[4], l_run[4];
#pragma unroll
    for (int r = 0; r < 4; ++r) { m_run[r] = -3.0e38f; l_run[r] = 0.f; }
    ffrag o[8];
    const ffrag z = {0.f, 0.f, 0.f, 0.f};
#pragma unroll
    for (int n = 0; n < 8; ++n) o[n] = z;

    unsigned short* psw = psb + w * (16 * 72);
    const int xorm = (m & 7) << 4;  // XOR swizzle bits for this lane's fragment rows

    unsigned int rem = uni;
    while (rem) {
        const int b = __builtin_ctz(rem);
        rem &= rem - 1;
        __syncthreads();  // prior compute done; LDS free (also covers prologue aliases)

        // ---- stage K block via DMA: LDS linear, global source inverse-swizzled ----
        // K LDS byte L holds kbp row (L>>8), col byte (L ^ ((L>>8 &7)<<4)) & 255
#pragma unroll
        for (int u = 0; u < 4; ++u) {
            const int L = (u * 256 + tid) * 16;
            const int row = L >> 8;
            const int sc = (L ^ ((row & 7) << 4)) & 255;
            gl_lds16(kbp + (size_t)(b * 64 + row) * 1024 + kv * 128 + (sc >> 1),
                     (unsigned char*)smem + L);
        }
        // ---- stage V^T block via DMA (rows = output dims, 128B each) ----
#pragma unroll
        for (int u = 0; u < 4; ++u) {
            const int L = (u * 256 + tid) * 16;
            const int row = L >> 7;
            const int sc = (L ^ ((row & 7) << 4)) & 127;
            gl_lds16(vtp + (size_t)(kv * 128 + row) * 2048 + b * 64 + (sc >> 1),
                     (unsigned char*)smem + 16384 + L);
        }
        __syncthreads();  // DMA drained (syncthreads waits vmcnt 0)

        // ---- QK^T: per wave 16 rows x 64 keys ----
        ffrag s[4];
#pragma unroll
        for (int j = 0; j < 4; ++j) s[j] = z;
        __builtin_amdgcn_s_setprio(1);
#pragma unroll
        for (int ks = 0; ks < 4; ++ks) {
#pragma unroll
            for (int j = 0; j < 4; ++j) {
                const int kb = (((j * 16 + m) << 8) + (ks << 6) + (quad << 4)) ^ xorm;
                const bfrag bk = *(const bfrag*)((const unsigned char*)ksb + kb);
                s[j] = __builtin_amdgcn_mfma_f32_16x16x32_bf16(aq[ks], bk, s[j], 0, 0, 0);
            }
        }
        __builtin_amdgcn_s_setprio(0);

        // ---- mask + online softmax (register m/l, wave-exclusive rows) ----
        const bool diag = (b == qt);
        float a_r[4];
#pragma unroll
        for (int r = 0; r < 4; ++r) {
            const int rloc = quad * 4 + r;
            const int rtile = wm + rloc;
            const bool selb = (selr[r] >> b) & 1u;
            float sv[4];
#pragma unroll
            for (int j = 0; j < 4; ++j) {
                const int col = j * 16 + m;
                const bool valid = selb && (!diag || col <= rtile);
                sv[j] = valid ? s[j][r] * SCALE : -3.0e38f;
            }
            float t = fmaxf(fmaxf(sv[0], sv[1]), fmaxf(sv[2], sv[3]));
            t = fmaxf(t, __shfl_xor(t, 1));
            t = fmaxf(t, __shfl_xor(t, 2));
            t = fmaxf(t, __shfl_xor(t, 4));
            t = fmaxf(t, __shfl_xor(t, 8));
            const float mo = m_run[r];
            const float mn = fmaxf(mo, t);
            a_r[r] = __expf(mo - mn);
            float sum = 0.f;
#pragma unroll
            for (int j = 0; j < 4; ++j) {
                const float p = (sv[j] > -1.0e30f) ? __expf(sv[j] - mn) : 0.f;
                psw[rloc * 72 + j * 16 + m] = f2b(p);
                sum += p;
            }
            sum += __shfl_xor(sum, 1);
            sum += __shfl_xor(sum, 2);
            sum += __shfl_xor(sum, 4);
            sum += __shfl_xor(sum, 8);
            l_run[r] = l_run[r] * a_r[r] + sum;
            m_run[r] = mn;
        }
#pragma unroll
        for (int n = 0; n < 8; ++n)
#pragma unroll
            for (int r = 0; r < 4; ++r) o[n][r] *= a_r[r];

        // ---- PV: O(16x128) += P(16x64) @ V(64x128); P via wave-private LDS ----
        __builtin_amdgcn_s_setprio(1);
#pragma unroll
        for (int ks = 0; ks < 2; ++ks) {
            const bfrag pa = *(const bfrag*)(psw + m * 72 + ks * 32 + quad * 8);
#pragma unroll
            for (int n = 0; n < 8; ++n) {
                const int vb = (((n * 16 + m) << 7) + (ks << 6) + (quad << 4)) ^ xorm;
                const bfrag bv = *(const bfrag*)((const unsigned char*)vsb + vb);
                o[n] = __builtin_amdgcn_mfma_f32_16x16x32_bf16(pa, bv, o[n], 0, 0, 0);
            }
        }
        __builtin_amdgcn_s_setprio(0);
    }

    // ---- epilogue ----
#pragma unroll
    for (int r = 0; r < 4; ++r) {
        const float inv = 1.f / l_run[r];
        float* op = out + ((size_t)((qbase + wm + quad * 4 + r) * NH + h)) * HD + m;
#pragma unroll
        for (int n = 0; n < 8; ++n) op[n * 16] = o[n][r] * inv;
    }
}

// ---------------- legacy VALU attention (fallback path) ----------------
__global__ __launch_bounds__(256) void attn_tile_kernel(const float* __restrict__ q,
                                                        const float* __restrict__ kptr,
                                                        const float* __restrict__ vptr,
                                                        const float* __restrict__ kblk,
                                                        float* __restrict__ out,
                                                        int kvstride) {
    __shared__ __align__(16) unsigned char smem[62464];
    unsigned short* ksb = (unsigned short*)smem;            // [64][136]
    unsigned short* vsb = (unsigned short*)(smem + 17408);  // [64][136]
    unsigned short* psb = (unsigned short*)(smem + 34816);  // [64][68]
    unsigned short* qsb = (unsigned short*)(smem + 43520);  // [64][136]
    float* mrow = (float*)(smem + 60928);
    float* lrow = (float*)(smem + 61184);
    float* arow = (float*)(smem + 61440);
    float* mnew = (float*)(smem + 61696);
    unsigned int* selm = (unsigned int*)(smem + 61952);
    float* qf  = (float*)smem;             // [64][132]
    float* kbf = (float*)(smem + 33792);   // [32][132]
    float* bsc = (float*)(smem + 50688);   // [64][33]

    const int qt = 31 - blockIdx.x;
    const int h = blockIdx.y;
    const int kv = h >> 2;
    const int qbase = qt * 64;
    const int tid = threadIdx.x;
    const int lane = tid & 63;
    const int w = tid >> 6;
    const int kl = lane & 15;
    const int ql = lane >> 4;

#pragma unroll
    for (int u = 0; u < 8; ++u) {
        const int idx = u * 1024 + tid * 4;
        const int qi = idx >> 7, d = idx & 127;
        *(float4*)(qf + qi * 132 + d) =
            *(const float4*)(q + ((size_t)((qbase + qi) * NH + h)) * HD + d);
    }
#pragma unroll
    for (int u = 0; u < 4; ++u) {
        const int idx = u * 1024 + tid * 4;
        const int b = idx >> 7, d = idx & 127;
        *(float4*)(kbf + b * 132 + d) =
            *(const float4*)(kblk + ((size_t)(kv * NBLK + b)) * HD + d);
    }
    __syncthreads();

    {
        float acc[4][2] = {};
#pragma unroll 4
        for (int d = 0; d < 128; d += 4) {
            float4 qv[4], kb2[2];
#pragma unroll
            for (int i = 0; i < 4; ++i) qv[i] = *(float4*)(qf + (ql + 4 * w + 16 * i) * 132 + d);
#pragma unroll
            for (int j = 0; j < 2; ++j) kb2[j] = *(float4*)(kbf + (kl + 16 * j) * 132 + d);
#pragma unroll
            for (int i = 0; i < 4; ++i)
#pragma unroll
                for (int j = 0; j < 2; ++j) acc[i][j] += dot4f(qv[i], kb2[j]);
        }
#pragma unroll
        for (int i = 0; i < 4; ++i)
#pragma unroll
            for (int j = 0; j < 2; ++j) {
                const int b = kl + 16 * j;
                if (b <= qt) bsc[(ql + 4 * w + 16 * i) * 33 + b] = acc[i][j];
            }
    }
    __syncthreads();

    if (tid < 64) {
        const int ns = (qt + 1 < TOPK) ? qt + 1 : TOPK;
        unsigned int sel = 0;
        const float* br = bsc + tid * 33;
        for (int t = 0; t < ns; ++t) {
            float best = -3.4e38f; int bi = 0;
            for (int b = 0; b <= qt; ++b)
                if (!((sel >> b) & 1u) && br[b] > best) { best = br[b]; bi = b; }
            sel |= 1u << bi;
        }
        selm[tid] = sel;
        mrow[tid] = -3.0e38f;
        lrow[tid] = 0.f;
    }
    __syncthreads();

    unsigned int uni = 0;
    {
        float tmp[32];
#pragma unroll
        for (int u = 0; u < 8; ++u) {
            const int idx = u * 1024 + tid * 4;
            *(float4*)(tmp + u * 4) = *(float4*)(qf + (idx >> 7) * 132 + (idx & 127));
        }
        for (int i = 0; i < 64; ++i) uni |= selm[i];
#pragma unroll
        for (int u = 0; u < 8; ++u) {
            const int idx = u * 1024 + tid * 4;
            const int qi = idx >> 7, d = idx & 127;
            ushort4 qu;
            qu.x = f2b(tmp[u * 4 + 0]); qu.y = f2b(tmp[u * 4 + 1]);
            qu.z = f2b(tmp[u * 4 + 2]); qu.w = f2b(tmp[u * 4 + 3]);
            *(ushort4*)(qsb + qi * 136 + d) = qu;
        }
    }
    __syncthreads();

    const int qi_r[4] = {ql + 4 * w, ql + 4 * w + 16, ql + 4 * w + 32, ql + 4 * w + 48};
    unsigned int selq[4];
#pragma unroll
    for (int i = 0; i < 4; ++i) selq[i] = selm[qi_r[i]];

    float O[4][8] = {};

    for (int b = 0; b <= qt; ++b) {
        if (!((uni >> b) & 1u)) continue;
        __syncthreads();
#pragma unroll
        for (int u = 0; u < 8; ++u) {
            const int idx = u * 1024 + tid * 4;
            const int r = idx >> 7, d = idx & 127;
            const size_t gof = (size_t)(b * 64 + r) * kvstride + kv * HD + d;
            const float4 k4 = *(const float4*)(kptr + gof);
            const float4 v4 = *(const float4*)(vptr + gof);
            ushort4 ku, vu;
            ku.x = f2b(k4.x); ku.y = f2b(k4.y); ku.z = f2b(k4.z); ku.w = f2b(k4.w);
            vu.x = f2b(v4.x); vu.y = f2b(v4.y); vu.z = f2b(v4.z); vu.w = f2b(v4.w);
            *(ushort4*)(ksb + r * 136 + d) = ku;
            *(ushort4*)(vsb + r * 136 + d) = vu;
        }
        __syncthreads();

        float S[4][4] = {};
#pragma unroll 4
        for (int d = 0; d < 128; d += 4) {
            float qv[4][4], kk4[4][4];
#pragma unroll
            for (int i = 0; i < 4; ++i) unpack4(*(uint2*)(qsb + qi_r[i] * 136 + d), qv[i]);
#pragma unroll
            for (int j = 0; j < 4; ++j) unpack4(*(uint2*)(ksb + (kl + 16 * j) * 136 + d), kk4[j]);
#pragma unroll
            for (int i = 0; i < 4; ++i)
#pragma unroll
                for (int j = 0; j < 4; ++j)
#pragma unroll
                    for (int e = 0; e < 4; ++e) S[i][j] += qv[i][e] * kk4[j][e];
        }

        const bool diag = (b == qt);
        float tm[4];
#pragma unroll
        for (int i = 0; i < 4; ++i) {
            const bool selb = (selq[i] >> b) & 1u;
#pragma unroll
            for (int j = 0; j < 4; ++j) {
                const int kj = kl + 16 * j;
                const bool valid = selb && (!diag || kj <= qi_r[i]);
                S[i][j] = valid ? S[i][j] * SCALE : -3.0e38f;
            }
            float t = fmaxf(fmaxf(S[i][0], S[i][1]), fmaxf(S[i][2], S[i][3]));
            t = fmaxf(t, __shfl_xor(t, 1));
            t = fmaxf(t, __shfl_xor(t, 2));
            t = fmaxf(t, __shfl_xor(t, 4));
            t = fmaxf(t, __shfl_xor(t, 8));
            tm[i] = t;
        }
        if (kl == 0) {
#pragma unroll
            for (int i = 0; i < 4; ++i) {
                const float mo = mrow[qi_r[i]];
                const float mn = fmaxf(mo, tm[i]);
                mrow[qi_r[i]] = mn;
                mnew[qi_r[i]] = mn;
                arow[qi_r[i]] = __expf(mo - mn);
            }
        }
        __syncthreads();

        float tl[4];
#pragma unroll
        for (int i = 0; i < 4; ++i) {
            const float mn = mnew[qi_r[i]];
            float sum = 0.f;
#pragma unroll
            for (int j = 0; j < 4; ++j) {
                const float p = (S[i][j] > -1.0e30f) ? __expf(S[i][j] - mn) : 0.f;
                psb[qi_r[i] * 68 + kl + 16 * j] = f2b(p);
                sum += p;
            }
            sum += __shfl_xor(sum, 1);
            sum += __shfl_xor(sum, 2);
            sum += __shfl_xor(sum, 4);
            sum += __shfl_xor(sum, 8);
            tl[i] = sum;
        }
        if (kl == 0) {
#pragma unroll
            for (int i = 0; i < 4; ++i)
                lrow[qi_r[i]] = lrow[qi_r[i]] * arow[qi_r[i]] + tl[i];
        }
#pragma unroll
        for (int i = 0; i < 4; ++i) {
            const float a = arow[qi_r[i]];
#pragma unroll
            for (int e = 0; e < 8; ++e) O[i][e] *= a;
        }
        __syncthreads();

#pragma unroll 4
        for (int kj = 0; kj < 64; ++kj) {
            float p[4];
#pragma unroll
            for (int i = 0; i < 4; ++i) {
                unsigned short us = psb[qi_r[i] * 68 + kj];
                p[i] = bitsf(((unsigned int)us) << 16);
            }
            float vv[8];
            unpack8(*(uint4*)(vsb + kj * 136 + kl * 8), vv);
#pragma unroll
            for (int i = 0; i < 4; ++i)
#pragma unroll
                for (int e = 0; e < 8; ++e) O[i][e] += p[i] * vv[e];
        }
    }
    __syncthreads();

#pragma unroll
    for (int i = 0; i < 4; ++i) {
        const float inv = 1.f / lrow[qi_r[i]];
        float4 o0, o1;
        o0.x = O[i][0] * inv; o0.y = O[i][1] * inv; o0.z = O[i][2] * inv; o0.w = O[i][3] * inv;
        o1.x = O[i][4] * inv; o1.y = O[i][5] * inv; o1.z = O[i][6] * inv; o1.w = O[i][7] * inv;
        float* op = out + ((size_t)((qbase + qi_r[i]) * NH + h)) * HD + kl * 8;
        *(float4*)op = o0;
        *(float4*)(op + 4) = o1;
    }
}

// ---------------- launch ----------------
extern "C" void kernel_launch(void* const* d_in, const int* in_sizes, int n_in,
                              void* d_out, int out_size, void* d_ws, size_t ws_size,
                              hipStream_t stream) {
    const float* x    = (const float*)d_in[0];
    const float* cosb = (const float*)d_in[1];
    const float* sinb = (const float*)d_in[2];
    const float* wq   = (const float*)d_in[3];
    const float* wk   = (const float*)d_in[4];
    const float* wv   = (const float*)d_in[5];
    const float* wo   = (const float*)d_in[6];

    unsigned char* ws = (unsigned char*)d_ws;
    const dim3 t256(256);

    const size_t MAIN_REQ = 184680448ull;  // 176 MB layout below
    if (ws_size >= MAIN_REQ) {
        // ---- main path: MFMA GEMMs + MFMA attention ----
        float*          qf     = (float*)(ws);                       // 32 MB
        float*          kvf    = (float*)(ws + 33554432ull);         // 16 MB (k cols 0..1023, v 1024..2047)
        float*          kblk   = (float*)(ws + 50331648ull);         // 128 KB
        unsigned short* x_hi   = (unsigned short*)(ws + 50462720ull); // 16 MB
        unsigned short* x_lo   = (unsigned short*)(ws + 67239936ull); // 16 MB
        float*          attn   = (float*)(ws + 50462720ull);          // 32 MB (aliases x_hi+x_lo; x dead)
        unsigned short* wqT_hi = (unsigned short*)(ws + 84017152ull); // 32 MB (later woT_hi)
        unsigned short* wqT_lo = (unsigned short*)(ws + 117571584ull);// 32 MB (later attn_bf)
        unsigned short* kvT_hi = (unsigned short*)(ws + 151126016ull);// 16 MB (later kb16)
        unsigned short* kvT_lo = (unsigned short*)(ws + 167903232ull);// 16 MB (later vt)
        unsigned short* woT_hi = wqT_hi;
        unsigned short* attnbf = wqT_lo;
        unsigned short* kb16   = kvT_hi;  // 4 MB bf16 K  [SEQ][1024] (kvT dead after kv gemm)
        unsigned short* vtb    = kvT_lo;  // 4 MB bf16 V^T [1024][SEQ]

        // x -> hi/lo bf16
        conv_hilo<<<SEQ * DIM / 4 / 256, t256, 0, stream>>>(x, x_hi, x_lo);
        // weight transposes (N x K, K=4096)
        transpose_conv<<<dim3(DIM / 32, DIM / 32), t256, 0, stream>>>(wq, wqT_hi, wqT_lo, DIM, DIM, 0);
        transpose_conv<<<dim3(KVDIM / 32, DIM / 32), t256, 0, stream>>>(wk, kvT_hi, kvT_lo, DIM, KVDIM, 0);
        transpose_conv<<<dim3(KVDIM / 32, DIM / 32), t256, 0, stream>>>(wv, kvT_hi, kvT_lo, DIM, KVDIM, KVDIM);

        // q = x @ wq (split, ~fp32)
        hipLaunchKernelGGL((mfma_gemm<true>), dim3(DIM / 128, SEQ / 128), t256, 0, stream,
                           x_hi, x_lo, wqT_hi, wqT_lo, qf, SEQ, DIM, DIM);
        // [k|v] = x @ [wk|wv] (split)
        hipLaunchKernelGGL((mfma_gemm<true>), dim3(2 * KVDIM / 128, SEQ / 128), t256, 0, stream,
                           x_hi, x_lo, kvT_hi, kvT_lo, kvf, SEQ, 2 * KVDIM, DIM);
        // wo transpose into freed wqT_hi region
        transpose_conv<<<dim3(DIM / 32, DIM / 32), t256, 0, stream>>>(wo, woT_hi, nullptr, DIM, DIM, 0);

        rope_kernel<<<(SEQ * NH * 64) / 256, t256, 0, stream>>>(qf, cosb, sinb, NH, NH * HD);
        rope_kernel<<<(SEQ * NKV * 64) / 256, t256, 0, stream>>>(kvf, cosb, sinb, NKV, 2 * KVDIM);
        blkmean_kernel<<<(NKV * NBLK * HD) / 256, t256, 0, stream>>>(kvf, kblk, 2 * KVDIM);

        // precompute bf16 K (row-major) and bf16 V transposed (kvT regions are dead now)
        kconv_kernel<<<(SEQ * KVDIM / 4) / 256, t256, 0, stream>>>(kvf, kb16);
        vtrans_kernel<<<dim3(SEQ / 64, KVDIM / 64), t256, 0, stream>>>(kvf, vtb);

        attn_mfma_kernel<<<dim3(NBLK, NH), t256, 0, stream>>>(qf, kb16, vtb, kblk, attn);

        // attn -> bf16, then out = attn @ wo (plain bf16)
        conv_hilo<<<SEQ * DIM / 4 / 256, t256, 0, stream>>>(attn, attnbf, nullptr);
        hipLaunchKernelGGL((mfma_gemm<false>), dim3(DIM / 128, SEQ / 128), t256, 0, stream,
                           attnbf, nullptr, woT_hi, nullptr, (float*)d_out, SEQ, DIM, DIM);
    } else {
        // ---- fallback: R3 fp32 pipeline (76 MB) ----
        float* qf   = (float*)ws;
        float* kf   = qf + (size_t)SEQ * DIM;
        float* vf   = kf + (size_t)SEQ * KVDIM;
        float* kblk = vf + (size_t)SEQ * KVDIM;
        float* attn = kblk + (size_t)NKV * NBLK * HD;

        gemm_kernel<<<dim3(DIM / 64, SEQ / 64), t256, 0, stream>>>(x, wq, qf, SEQ, DIM, DIM);
        gemm_kernel<<<dim3(KVDIM / 64, SEQ / 64), t256, 0, stream>>>(x, wk, kf, SEQ, KVDIM, DIM);
        gemm_kernel<<<dim3(KVDIM / 64, SEQ / 64), t256, 0, stream>>>(x, wv, vf, SEQ, KVDIM, DIM);
        rope_kernel<<<(SEQ * NH * 64) / 256, t256, 0, stream>>>(qf, cosb, sinb, NH, NH * HD);
        rope_kernel<<<(SEQ * NKV * 64) / 256, t256, 0, stream>>>(kf, cosb, sinb, NKV, KVDIM);
        blkmean_kernel<<<(NKV * NBLK * HD) / 256, t256, 0, stream>>>(kf, kblk, KVDIM);
        attn_tile_kernel<<<dim3(NBLK, NH), t256, 0, stream>>>(qf, kf, vf, kblk, attn, KVDIM);
        gemm_kernel<<<dim3(DIM / 64, SEQ / 64), t256, 0, stream>>>(attn, wo, (float*)d_out, SEQ, DIM, DIM);
    }
}